// Round 6
// baseline (246.666 us; speedup 1.0000x reference)
//
#include <hip/hip_runtime.h>

#define BATCH   16
#define CDIM    256
#define NPTS    16384      // B*H*W
#define KCODES  8192
#define NELEM   4194304    // B*C*H*W
#define ESCALE  4096.0f
#define MARGIN  0.5f       // in S = 4096*dot units (worst-case error ~0.33)
#define PPB     32         // points per (group,chunk) batch
#define NCHUNK  8          // chunks per group

typedef _Float16 f16;
typedef _Float16 f16x8 __attribute__((ext_vector_type(8)));
typedef _Float16 f16x4 __attribute__((ext_vector_type(4)));
typedef float    f32x4 __attribute__((ext_vector_type(4)));

__device__ __forceinline__ void gload16(const void* g, void* l) {
    __builtin_amdgcn_global_load_lds(
        (const __attribute__((address_space(1))) unsigned int*)g,
        (__attribute__((address_space(3))) unsigned int*)l, 16, 0, 0);
}

// ---------------------------------------------------------------------------
// prep_z: zz[n] + z16[n][c] (verified) + compact fp32 copy zc[n][c]
// ---------------------------------------------------------------------------
__global__ __launch_bounds__(256) void k_prep_z(const float* __restrict__ z,
                                                f16* __restrict__ z16,
                                                float* __restrict__ zz,
                                                float* __restrict__ zc) {
    __shared__ f16 tile[64][264];
    __shared__ float tile32[64][260];
    __shared__ float red[4][64];
    const int n0 = blockIdx.x * 64;
    const int b = n0 >> 10, hw0 = n0 & 1023;
    const int p = threadIdx.x & 63, g = threadIdx.x >> 6;
    const float* zb = z + b * 262144 + hw0 + p;
    float s = 0.f;
    for (int c = g * 64; c < g * 64 + 64; ++c) {
        float v = zb[c * 1024];
        s = fmaf(v, v, s);
        tile[p][c] = (f16)v;
        tile32[p][c] = v;
    }
    red[g][p] = s;
    __syncthreads();
    if (g == 0) zz[n0 + p] = (red[0][p] + red[1][p]) + (red[2][p] + red[3][p]);
    const int r = threadIdx.x >> 2, q = threadIdx.x & 3;
    f16* dst = z16 + (size_t)(n0 + r) * 256 + q * 64;
    #pragma unroll
    for (int j = 0; j < 8; ++j)
        *(f16x8*)(dst + j * 8) = *(const f16x8*)(&tile[r][q * 64 + j * 8]);
    if (zc) {
        const int w = threadIdx.x >> 6, l = threadIdx.x & 63;
        #pragma unroll
        for (int rr = 0; rr < 16; ++rr) {
            const int row = w * 16 + rr;
            *(float4*)(zc + (size_t)(n0 + row) * 256 + l * 4) =
                *(const float4*)(&tile32[row][l * 4]);
        }
    }
}

// ---------------------------------------------------------------------------
// prep_e: e16[k][c] = f16(emb * 4096)
// ---------------------------------------------------------------------------
__global__ __launch_bounds__(256) void k_prep_e(const float* __restrict__ emb,
                                                f16* __restrict__ e16) {
    const int i = (blockIdx.x * 256 + threadIdx.x) * 4;
    float4 v = *(const float4*)(emb + i);
    f16x4 o = {(f16)(v.x * ESCALE), (f16)(v.y * ESCALE),
               (f16)(v.z * ESCALE), (f16)(v.w * ESCALE)};
    *(f16x4*)(e16 + i) = o;
}

// ---------------------------------------------------------------------------
// gemm: S = z16 @ e16^T.  8-phase schedule (T3+T4+T5): per K-tile 8 phases of
// {ds_read subtile -> s_barrier -> lgkmcnt(0) -> setprio(1) 16xMFMA setprio(0)
//  -> s_barrier}; 2-tile-deep prefetch so boundary vmcnt waits only for loads
// issued a full tile ago.  Raw s_barrier (no __syncthreads vmcnt(0) drain).
// Fragment math + staging + epilogue identical to the R5-verified kernel.
// ---------------------------------------------------------------------------
__device__ __forceinline__ void stage_tile(const f16* zg, const f16* eg,
                                           f16* Ab, f16* Bb, int t, int kt) {
    #pragma unroll
    for (int pp = 0; pp < 4; ++pp) {
        const int gi  = pp * 512 + t;
        const int row = gi >> 3;
        const int kc  = (gi & 7) ^ (row & 7);
        const size_t goff = (size_t)row * 256 + (size_t)kt * 64 + kc * 8;
        gload16(zg + goff, (char*)Ab + gi * 16);
        gload16(eg + goff, (char*)Bb + gi * 16);
    }
}

__global__ __launch_bounds__(512, 2) void k_gemm(const f16* __restrict__ z16,
                                                 const f16* __restrict__ e16,
                                                 f16* __restrict__ gmaxT) {
    __shared__ f16 As[2][16384];
    __shared__ f16 Bs[2][16384];
    const int bid = blockIdx.x;
    const int bm = bid >> 5, bn = bid & 31;
    const size_t m0 = (size_t)bm * 256, n0 = (size_t)bn * 256;
    const int t = threadIdx.x, lane = t & 63, w = t >> 6;
    const int wm = w >> 2, wn = w & 3;

    const f16* zg = z16 + m0 * 256;
    const f16* eg = e16 + n0 * 256;

    f32x4 acc[8][4] = {};

    // prologue: T0 -> buf0 (waited), T1 -> buf1 (left in flight)
    stage_tile(zg, eg, As[0], Bs[0], t, 0);
    __builtin_amdgcn_sched_barrier(0);
    asm volatile("s_waitcnt vmcnt(0)" ::: "memory");
    __builtin_amdgcn_sched_barrier(0);
    stage_tile(zg, eg, As[1], Bs[1], t, 1);
    __builtin_amdgcn_sched_barrier(0);
    __builtin_amdgcn_s_barrier();

    #pragma unroll
    for (int kt = 0; kt < 4; ++kt) {
        const char* Ab = (const char*)As[kt & 1];
        const char* Bb = (const char*)Bs[kt & 1];
        #pragma unroll
        for (int kk = 0; kk < 2; ++kk) {
            const int kc = kk * 4 + (lane >> 4);
            f16x8 bfr[4], alo[4], ahi[4];
            // ---- phase A: read B-frags + A-low, MFMA mr0-3 ----
            #pragma unroll
            for (int nr = 0; nr < 4; ++nr) {
                const int row = wn * 64 + nr * 16 + (lane & 15);
                bfr[nr] = *(const f16x8*)(Bb + row * 128 + ((kc ^ (row & 7)) << 4));
            }
            #pragma unroll
            for (int mr = 0; mr < 4; ++mr) {
                const int row = wm * 128 + mr * 16 + (lane & 15);
                alo[mr] = *(const f16x8*)(Ab + row * 128 + ((kc ^ (row & 7)) << 4));
            }
            __builtin_amdgcn_s_barrier();
            asm volatile("s_waitcnt lgkmcnt(0)" ::: "memory");
            __builtin_amdgcn_sched_barrier(0);
            __builtin_amdgcn_s_setprio(1);
            #pragma unroll
            for (int mr = 0; mr < 4; ++mr)
                #pragma unroll
                for (int nr = 0; nr < 4; ++nr)
                    acc[mr][nr] = __builtin_amdgcn_mfma_f32_16x16x32_f16(
                        alo[mr], bfr[nr], acc[mr][nr], 0, 0, 0);
            __builtin_amdgcn_s_setprio(0);
            __builtin_amdgcn_sched_barrier(0);
            __builtin_amdgcn_s_barrier();
            // ---- phase B: read A-high, MFMA mr4-7 (reuse bfr) ----
            #pragma unroll
            for (int mr = 0; mr < 4; ++mr) {
                const int row = wm * 128 + (mr + 4) * 16 + (lane & 15);
                ahi[mr] = *(const f16x8*)(Ab + row * 128 + ((kc ^ (row & 7)) << 4));
            }
            __builtin_amdgcn_s_barrier();
            asm volatile("s_waitcnt lgkmcnt(0)" ::: "memory");
            __builtin_amdgcn_sched_barrier(0);
            __builtin_amdgcn_s_setprio(1);
            #pragma unroll
            for (int mr = 0; mr < 4; ++mr)
                #pragma unroll
                for (int nr = 0; nr < 4; ++nr)
                    acc[mr + 4][nr] = __builtin_amdgcn_mfma_f32_16x16x32_f16(
                        ahi[mr], bfr[nr], acc[mr + 4][nr], 0, 0, 0);
            __builtin_amdgcn_s_setprio(0);
            __builtin_amdgcn_sched_barrier(0);
            __builtin_amdgcn_s_barrier();
        }
        // ---- tile boundary: wait tile kt+1 (issued >=1 tile ago), then
        //      refill the just-freed buffer with tile kt+2 ----
        if (kt < 3) {
            asm volatile("s_waitcnt vmcnt(0)" ::: "memory");
            __builtin_amdgcn_sched_barrier(0);
        }
        if (kt < 2) {
            stage_tile(zg, eg, (f16*)As[kt & 1], (f16*)Bs[kt & 1], t, kt + 2);
            __builtin_amdgcn_sched_barrier(0);
        }
        __builtin_amdgcn_s_barrier();
    }

    // epilogue: per-point max over this wave's 64 codes (verified)
    const int g = bn * 4 + wn;
    #pragma unroll
    for (int mr = 0; mr < 8; ++mr) {
        #pragma unroll
        for (int q = 0; q < 4; ++q) {
            float v = acc[mr][0][q];
            v = fmaxf(v, acc[mr][1][q]);
            v = fmaxf(v, acc[mr][2][q]);
            v = fmaxf(v, acc[mr][3][q]);
            v = fmaxf(v, __shfl_xor(v, 1));
            v = fmaxf(v, __shfl_xor(v, 2));
            v = fmaxf(v, __shfl_xor(v, 4));
            v = fmaxf(v, __shfl_xor(v, 8));
            if ((lane & 15) == 0) {
                const int p = wm * 128 + mr * 16 + ((lane >> 4) << 2) + q;
                gmaxT[(size_t)g * 16384 + m0 + p] = (f16)v;
            }
        }
    }
}

// ---------------------------------------------------------------------------
// pmax: thr[n] = max_g gmaxT[g][n] - MARGIN   (verified)
// ---------------------------------------------------------------------------
__global__ __launch_bounds__(256) void k_pmax(const f16* __restrict__ gmaxT,
                                              float* __restrict__ thr) {
    const int n = blockIdx.x * 256 + threadIdx.x;
    float m = -1e30f;
    #pragma unroll 16
    for (int g = 0; g < 128; ++g)
        m = fmaxf(m, (float)gmaxT[(size_t)g * 16384 + n]);
    thr[n] = m - MARGIN;
}

// ---------------------------------------------------------------------------
// build: compact candidate lists, no atomics (verified)
// ---------------------------------------------------------------------------
__global__ __launch_bounds__(256) void k_build(const f16* __restrict__ gmaxT,
                                               const float* __restrict__ thr,
                                               unsigned* __restrict__ cnt,
                                               unsigned* __restrict__ list) {
    __shared__ unsigned wsum[4];
    const int g = blockIdx.x;
    const int t = threadIdx.x, lane = t & 63, w = t >> 6;
    const f16* row = gmaxT + (size_t)g * 16384;
    unsigned* gl = list + (size_t)g * 16384;
    unsigned run = 0;
    for (int c = 0; c < 64; ++c) {
        const int n = c * 256 + t;
        const bool f = (float)row[n] >= thr[n];
        const unsigned long long mk = __ballot(f);
        if (lane == 0) wsum[w] = (unsigned)__popcll(mk);
        __syncthreads();
        const unsigned w0 = wsum[0], w1 = wsum[1], w2 = wsum[2], w3 = wsum[3];
        if (f) {
            const unsigned wexcl = (w > 0 ? w0 : 0u) + (w > 1 ? w1 : 0u) + (w > 2 ? w2 : 0u);
            const unsigned rank = (unsigned)__popcll(mk & ((1ull << lane) - 1ull));
            gl[run + wexcl + rank] = (unsigned)n;
        }
        run += w0 + w1 + w2 + w3;
        __syncthreads();
    }
    if (t == 0) cnt[g] = run;
}

// ---------------------------------------------------------------------------
// rescore2 (group-major, verified)
// ---------------------------------------------------------------------------
__global__ __launch_bounds__(256) void k_rescore2(const float* __restrict__ emb,
                                                  const float* __restrict__ zc,
                                                  const float* __restrict__ zz,
                                                  const unsigned* __restrict__ cnt,
                                                  const unsigned* __restrict__ list,
                                                  unsigned long long* __restrict__ best) {
    __shared__ float es[64 * 260];
    __shared__ float zs[4][256];
    const int g = blockIdx.x >> 3, c = blockIdx.x & 7;
    const unsigned nct = cnt[g];
    if (nct <= (unsigned)(c * PPB)) return;

    const int t = threadIdx.x, lane = t & 63, w = t >> 6;
    {
        const float* eg = emb + (size_t)g * 64 * 256;
        for (int i = t * 4; i < 16384; i += 1024) {
            const float4 v = *(const float4*)(eg + i);
            const int row = i >> 8, col = i & 255;
            *(float4*)(&es[row * 260 + col]) = v;
        }
    }
    __syncthreads();

    const unsigned* gl = list + g * 16384;
    for (unsigned base = c * PPB; base < nct; base += NCHUNK * PPB) {
        #pragma unroll 1
        for (int j = 0; j < 8; ++j) {
            const unsigned i = base + w * 8 + j;
            if (i >= nct || i >= base + PPB) continue;
            const unsigned n = gl[i];
            const float4 zv = *(const float4*)(zc + (size_t)n * 256 + lane * 4);
            *(float4*)(&zs[w][lane * 4]) = zv;
            const float zzv = zz[n];
            const float4* zr = (const float4*)(&zs[w][0]);
            const float4* er = (const float4*)(&es[lane * 260]);
            float4 a = {0.f, 0.f, 0.f, 0.f};
            #pragma unroll 8
            for (int c4 = 0; c4 < 64; ++c4) {
                const float4 e4 = er[c4];
                const float4 z4 = zr[c4];
                a.x = fmaf(z4.x, e4.x, a.x);
                a.y = fmaf(z4.y, e4.y, a.y);
                a.z = fmaf(z4.z, e4.z, a.z);
                a.w = fmaf(z4.w, e4.w, a.w);
            }
            const float dot = (a.x + a.y) + (a.z + a.w);
            const float d = fmaf(-2.f, dot, zzv);
            unsigned long long key =
                ((unsigned long long)__float_as_uint(d) << 32) | (unsigned)(g * 64 + lane);
            #pragma unroll
            for (int s = 1; s < 64; s <<= 1) {
                const unsigned long long o = __shfl_xor(key, s);
                if (o < key) key = o;
            }
            if (lane == 0) atomicMin(&best[n], key);
        }
    }
}

// ---------------------------------------------------------------------------
// rescore (fallback, verified)
// ---------------------------------------------------------------------------
__global__ __launch_bounds__(256) void k_rescore(const float* __restrict__ z,
                                                 const float* __restrict__ emb,
                                                 const float* __restrict__ zz,
                                                 const f16* __restrict__ gmaxT,
                                                 unsigned long long* __restrict__ best) {
    __shared__ float zsh[16][260];
    const int n0 = blockIdx.x * 16;
    const int b = n0 >> 10, hw0 = n0 & 1023;
    const int t = threadIdx.x, lane = t & 63, w = t >> 6;
    {
        const int p = t & 15, cq = t >> 4;
        const float* zp = z + (size_t)b * 262144 + hw0 + p;
        #pragma unroll
        for (int c = cq * 16; c < cq * 16 + 16; ++c)
            zsh[p][c] = zp[(size_t)c * 1024];
    }
    __syncthreads();
    for (int p = w; p < 16; p += 4) {
        const int n = n0 + p;
        const float g0 = (float)gmaxT[(size_t)lane * 16384 + n];
        const float g1 = (float)gmaxT[(size_t)(lane + 64) * 16384 + n];
        float m = fmaxf(g0, g1);
        #pragma unroll
        for (int s = 1; s < 64; s <<= 1) m = fmaxf(m, __shfl_xor(m, s));
        const float thr = m - MARGIN;
        unsigned long long f0 = __ballot(g0 >= thr);
        unsigned long long f1 = __ballot(g1 >= thr);
        const float zzv = zz[n];
        const float4* zr = (const float4*)(&zsh[p][0]);
        unsigned long long key = ~0ull;
        while (f0 | f1) {
            int g;
            if (f0) { g = __ffsll(f0) - 1; f0 &= f0 - 1; }
            else    { g = 64 + __ffsll(f1) - 1; f1 &= f1 - 1; }
            const float4* er = (const float4*)(emb + ((size_t)(g * 64 + lane) << 8));
            float4 a = {0.f, 0.f, 0.f, 0.f};
            #pragma unroll 8
            for (int c4 = 0; c4 < 64; ++c4) {
                const float4 e4 = er[c4];
                const float4 z4 = zr[c4];
                a.x = fmaf(z4.x, e4.x, a.x);
                a.y = fmaf(z4.y, e4.y, a.y);
                a.z = fmaf(z4.z, e4.z, a.z);
                a.w = fmaf(z4.w, e4.w, a.w);
            }
            const float dot = (a.x + a.y) + (a.z + a.w);
            const float d = fmaf(-2.f, dot, zzv);
            const unsigned long long kk =
                ((unsigned long long)__float_as_uint(d) << 32) | (unsigned)(g * 64 + lane);
            if (kk < key) key = kk;
        }
        #pragma unroll
        for (int s = 1; s < 64; s <<= 1) {
            const unsigned long long o = __shfl_xor(key, s);
            if (o < key) key = o;
        }
        if (lane == 0) best[n] = key;
    }
}

// ---------------------------------------------------------------------------
// out + loss (unchanged — verified exact)
// ---------------------------------------------------------------------------
__global__ __launch_bounds__(256) void k_out(const float* __restrict__ z,
                                             const float* __restrict__ emb,
                                             const unsigned long long* __restrict__ best,
                                             float* __restrict__ out0,
                                             float* __restrict__ out2,
                                             double* __restrict__ loss) {
    const int n0 = blockIdx.x * 64;
    const int b = n0 >> 10, hw0 = n0 & 1023;
    const int p = threadIdx.x & 63, cg = threadIdx.x >> 6;
    const int n = n0 + p;
    const int idx = (int)(unsigned)(best[n] & 0xffffffffull);
    if (threadIdx.x < 64)
        out2[n0 + threadIdx.x] =
            (float)(int)(unsigned)(best[n0 + threadIdx.x] & 0xffffffffull);

    const float* zb = z + b * 262144 + hw0 + p;
    float*       ob = out0 + b * 262144 + hw0 + p;
    const float* eb = emb + idx * 256;
    double ls = 0.0;
    #pragma unroll 4
    for (int c = cg * 64; c < cg * 64 + 64; ++c) {
        float zp = zb[c * 1024];
        float e  = eb[c];
        float diff = e - zp;
        ob[c * 1024] = zp + diff;
        float l = zp - e;
        ls += (double)l * (double)l;
    }
    __shared__ double red[256];
    red[threadIdx.x] = ls;
    __syncthreads();
    for (int s = 128; s > 0; s >>= 1) {
        if (threadIdx.x < s) red[threadIdx.x] += red[threadIdx.x + s];
        __syncthreads();
    }
    if (threadIdx.x == 0) atomicAdd(loss, red[0]);
}

__global__ void k_loss(const double* __restrict__ loss, float* __restrict__ out1) {
    float m = (float)(*loss / (double)NELEM);
    out1[0] = 0.25f * m + m;
}

// ---------------------------------------------------------------------------
extern "C" void kernel_launch(void* const* d_in, const int* in_sizes, int n_in,
                              void* d_out, int out_size, void* d_ws, size_t ws_size,
                              hipStream_t stream) {
    const float* z   = (const float*)d_in[0];
    const float* emb = (const float*)d_in[1];
    float* out  = (float*)d_out;
    float* out0 = out;
    float* out1 = out + NELEM;
    float* out2 = out + NELEM + 1;

    // out0 (16 MB) scratch: z16 (8 MB) | e16 (4 MB) | gmaxT (4 MB).
    // After gemm: z16 region -> candidate lists (8 MB); e16 region -> thr (64 KB).
    f16* z16    = (f16*)out0;
    f16* e16    = (f16*)((char*)out0 + 8388608);
    f16* gmaxT  = (f16*)((char*)out0 + 12582912);
    unsigned* list = (unsigned*)out0;
    float* thr  = (float*)((char*)out0 + 8388608);

    const size_t ZC_BYTES = 16777216;
    const bool fast = ws_size >= ZC_BYTES + 65536 + 131072 + 1024;

    if (fast) {
        float* zc = (float*)d_ws;                                        // 16 MB
        float* zzp = (float*)((char*)d_ws + ZC_BYTES);                   // 64 KB
        unsigned long long* best =
            (unsigned long long*)((char*)d_ws + ZC_BYTES + 65536);       // 128 KB
        unsigned* cnt = (unsigned*)((char*)d_ws + ZC_BYTES + 65536 + 131072);
        double* loss  = (double*)((char*)d_ws + ZC_BYTES + 65536 + 131072 + 512);

        hipMemsetAsync(best, 0xFF, NPTS * 8, stream);
        hipMemsetAsync(loss, 0, 8, stream);
        k_prep_z<<<256, 256, 0, stream>>>(z, z16, zzp, zc);
        k_prep_e<<<2048, 256, 0, stream>>>(emb, e16);
        k_gemm<<<2048, 512, 0, stream>>>(z16, e16, gmaxT);
        k_pmax<<<64, 256, 0, stream>>>(gmaxT, thr);
        k_build<<<128, 256, 0, stream>>>(gmaxT, thr, cnt, list);
        k_rescore2<<<128 * NCHUNK, 256, 0, stream>>>(emb, zc, zzp, cnt, list, best);
        k_out<<<256, 256, 0, stream>>>(z, emb, best, out0, out2, loss);
        k_loss<<<1, 1, 0, stream>>>(loss, out1);
    } else {
        float* zzp = (float*)d_ws;
        unsigned long long* best =
            (unsigned long long*)((char*)d_ws + 65536);
        double* loss = (double*)((char*)d_ws + 65536 + 131072);

        hipMemsetAsync(loss, 0, 8, stream);
        k_prep_z<<<256, 256, 0, stream>>>(z, z16, zzp, nullptr);
        k_prep_e<<<2048, 256, 0, stream>>>(emb, e16);
        k_gemm<<<2048, 512, 0, stream>>>(z16, e16, gmaxT);
        k_rescore<<<1024, 256, 0, stream>>>(z, emb, zzp, gmaxT, best);
        k_out<<<256, 256, 0, stream>>>(z, emb, best, out0, out2, loss);
        k_loss<<<1, 1, 0, stream>>>(loss, out1);
    }
}

// Round 7
// 242.683 us; speedup vs baseline: 1.0164x; 1.0164x over previous
//
#include <hip/hip_runtime.h>

#define BATCH   16
#define CDIM    256
#define NPTS    16384      // B*H*W
#define KCODES  8192
#define NELEM   4194304    // B*C*H*W
#define ESCALE  4096.0f
#define MARGIN  0.5f       // in S = 4096*dot units (worst-case error ~0.33)
#define PPB     32         // points per (group,chunk) batch
#define NCHUNK  8          // chunks per group

typedef _Float16 f16;
typedef _Float16 f16x8 __attribute__((ext_vector_type(8)));
typedef _Float16 f16x4 __attribute__((ext_vector_type(4)));
typedef float    f32x4 __attribute__((ext_vector_type(4)));

__device__ __forceinline__ void gload16(const void* g, void* l) {
    __builtin_amdgcn_global_load_lds(
        (const __attribute__((address_space(1))) unsigned int*)g,
        (__attribute__((address_space(3))) unsigned int*)l, 16, 0, 0);
}

// ---------------------------------------------------------------------------
// prep_z: zz[n] + z16[n][c] (verified) + compact fp32 copy zc[n][c]
// ---------------------------------------------------------------------------
__global__ __launch_bounds__(256) void k_prep_z(const float* __restrict__ z,
                                                f16* __restrict__ z16,
                                                float* __restrict__ zz,
                                                float* __restrict__ zc) {
    __shared__ f16 tile[64][264];
    __shared__ float tile32[64][260];
    __shared__ float red[4][64];
    const int n0 = blockIdx.x * 64;
    const int b = n0 >> 10, hw0 = n0 & 1023;
    const int p = threadIdx.x & 63, g = threadIdx.x >> 6;
    const float* zb = z + b * 262144 + hw0 + p;
    float s = 0.f;
    for (int c = g * 64; c < g * 64 + 64; ++c) {
        float v = zb[c * 1024];
        s = fmaf(v, v, s);
        tile[p][c] = (f16)v;
        tile32[p][c] = v;
    }
    red[g][p] = s;
    __syncthreads();
    if (g == 0) zz[n0 + p] = (red[0][p] + red[1][p]) + (red[2][p] + red[3][p]);
    const int r = threadIdx.x >> 2, q = threadIdx.x & 3;
    f16* dst = z16 + (size_t)(n0 + r) * 256 + q * 64;
    #pragma unroll
    for (int j = 0; j < 8; ++j)
        *(f16x8*)(dst + j * 8) = *(const f16x8*)(&tile[r][q * 64 + j * 8]);
    if (zc) {
        const int w = threadIdx.x >> 6, l = threadIdx.x & 63;
        #pragma unroll
        for (int rr = 0; rr < 16; ++rr) {
            const int row = w * 16 + rr;
            *(float4*)(zc + (size_t)(n0 + row) * 256 + l * 4) =
                *(const float4*)(&tile32[row][l * 4]);
        }
    }
}

// ---------------------------------------------------------------------------
// prep_e: e16[k][c] = f16(emb * 4096)
// ---------------------------------------------------------------------------
__global__ __launch_bounds__(256) void k_prep_e(const float* __restrict__ emb,
                                                f16* __restrict__ e16) {
    const int i = (blockIdx.x * 256 + threadIdx.x) * 4;
    float4 v = *(const float4*)(emb + i);
    f16x4 o = {(f16)(v.x * ESCALE), (f16)(v.y * ESCALE),
               (f16)(v.z * ESCALE), (f16)(v.w * ESCALE)};
    *(f16x4*)(e16 + i) = o;
}

// ---------------------------------------------------------------------------
// gemm: S = z16 @ e16^T.  m97-proven structure: 128x128 tile, 4 waves
// (wave-tile 64x64), BK=64 single-buffered (32 KB LDS -> ~4 blocks/CU),
// gload_lds w16 with inverse-swizzled source, XOR-swizzled ds_read_b128,
// plain 2-barrier K-loop (compiler waitcnt).  XCD-aware block swizzle
// (8192 blocks, 8192%8==0 -> simple bijective form).
// Epilogue: each wave owns one 64-code group -> gmaxT[g][n].
// ---------------------------------------------------------------------------
__global__ __launch_bounds__(256, 4) void k_gemm(const f16* __restrict__ z16,
                                                 const f16* __restrict__ e16,
                                                 f16* __restrict__ gmaxT) {
    __shared__ f16 As[8192];   // [128 rows][64 k] = 16 KB
    __shared__ f16 Bs[8192];   // 16 KB
    // XCD swizzle: 8192 blocks, 1024 per XCD chunk
    const int swz = (blockIdx.x & 7) * 1024 + (blockIdx.x >> 3);
    const int bm = swz >> 6, bn = swz & 63;
    const size_t m0 = (size_t)bm * 128, n0 = (size_t)bn * 128;
    const int t = threadIdx.x, lane = t & 63, w = t >> 6;
    const int wm = w >> 1, wn = w & 1;        // 2x2 waves, wave tile 64x64

    const f16* zg = z16 + m0 * 256;
    const f16* eg = e16 + n0 * 256;

    f32x4 acc[4][4] = {};

    for (int kt = 0; kt < 4; ++kt) {
        // stage: 128 rows x 64 k, 1024 granules of 16B per matrix, 4/thread
        #pragma unroll
        for (int pp = 0; pp < 4; ++pp) {
            const int gi  = pp * 256 + t;
            const int row = gi >> 3;
            const int kc  = (gi & 7) ^ (row & 7);  // inverse swizzle on source
            const size_t goff = (size_t)row * 256 + (size_t)kt * 64 + kc * 8;
            gload16(zg + goff, (char*)As + gi * 16);
            gload16(eg + goff, (char*)Bs + gi * 16);
        }
        __syncthreads();
        #pragma unroll
        for (int kk = 0; kk < 2; ++kk) {
            f16x8 a[4], bf[4];
            const int kc = kk * 4 + (lane >> 4);
            #pragma unroll
            for (int mr = 0; mr < 4; ++mr) {
                const int row = wm * 64 + mr * 16 + (lane & 15);
                a[mr] = *(const f16x8*)((const char*)As + row * 128 + ((kc ^ (row & 7)) << 4));
            }
            #pragma unroll
            for (int nr = 0; nr < 4; ++nr) {
                const int row = wn * 64 + nr * 16 + (lane & 15);
                bf[nr] = *(const f16x8*)((const char*)Bs + row * 128 + ((kc ^ (row & 7)) << 4));
            }
            #pragma unroll
            for (int mr = 0; mr < 4; ++mr)
                #pragma unroll
                for (int nr = 0; nr < 4; ++nr)
                    acc[mr][nr] = __builtin_amdgcn_mfma_f32_16x16x32_f16(
                        a[mr], bf[nr], acc[mr][nr], 0, 0, 0);
        }
        __syncthreads();
    }

    // epilogue: per-point max over this wave's 64 codes (one group)
    const int g = bn * 2 + wn;
    #pragma unroll
    for (int mr = 0; mr < 4; ++mr) {
        #pragma unroll
        for (int q = 0; q < 4; ++q) {
            float v = acc[mr][0][q];
            v = fmaxf(v, acc[mr][1][q]);
            v = fmaxf(v, acc[mr][2][q]);
            v = fmaxf(v, acc[mr][3][q]);
            v = fmaxf(v, __shfl_xor(v, 1));
            v = fmaxf(v, __shfl_xor(v, 2));
            v = fmaxf(v, __shfl_xor(v, 4));
            v = fmaxf(v, __shfl_xor(v, 8));
            if ((lane & 15) == 0) {
                const int p = wm * 64 + mr * 16 + ((lane >> 4) << 2) + q;
                gmaxT[(size_t)g * 16384 + m0 + p] = (f16)v;
            }
        }
    }
}

// ---------------------------------------------------------------------------
// pmax: thr[n] = max_g gmaxT[g][n] - MARGIN   (verified)
// ---------------------------------------------------------------------------
__global__ __launch_bounds__(256) void k_pmax(const f16* __restrict__ gmaxT,
                                              float* __restrict__ thr) {
    const int n = blockIdx.x * 256 + threadIdx.x;
    float m = -1e30f;
    #pragma unroll 16
    for (int g = 0; g < 128; ++g)
        m = fmaxf(m, (float)gmaxT[(size_t)g * 16384 + n]);
    thr[n] = m - MARGIN;
}

// ---------------------------------------------------------------------------
// build: compact candidate lists, no atomics (verified)
// ---------------------------------------------------------------------------
__global__ __launch_bounds__(256) void k_build(const f16* __restrict__ gmaxT,
                                               const float* __restrict__ thr,
                                               unsigned* __restrict__ cnt,
                                               unsigned* __restrict__ list) {
    __shared__ unsigned wsum[4];
    const int g = blockIdx.x;
    const int t = threadIdx.x, lane = t & 63, w = t >> 6;
    const f16* row = gmaxT + (size_t)g * 16384;
    unsigned* gl = list + (size_t)g * 16384;
    unsigned run = 0;
    for (int c = 0; c < 64; ++c) {
        const int n = c * 256 + t;
        const bool f = (float)row[n] >= thr[n];
        const unsigned long long mk = __ballot(f);
        if (lane == 0) wsum[w] = (unsigned)__popcll(mk);
        __syncthreads();
        const unsigned w0 = wsum[0], w1 = wsum[1], w2 = wsum[2], w3 = wsum[3];
        if (f) {
            const unsigned wexcl = (w > 0 ? w0 : 0u) + (w > 1 ? w1 : 0u) + (w > 2 ? w2 : 0u);
            const unsigned rank = (unsigned)__popcll(mk & ((1ull << lane) - 1ull));
            gl[run + wexcl + rank] = (unsigned)n;
        }
        run += w0 + w1 + w2 + w3;
        __syncthreads();
    }
    if (t == 0) cnt[g] = run;
}

// ---------------------------------------------------------------------------
// rescore2 (group-major, verified)
// ---------------------------------------------------------------------------
__global__ __launch_bounds__(256) void k_rescore2(const float* __restrict__ emb,
                                                  const float* __restrict__ zc,
                                                  const float* __restrict__ zz,
                                                  const unsigned* __restrict__ cnt,
                                                  const unsigned* __restrict__ list,
                                                  unsigned long long* __restrict__ best) {
    __shared__ float es[64 * 260];
    __shared__ float zs[4][256];
    const int g = blockIdx.x >> 3, c = blockIdx.x & 7;
    const unsigned nct = cnt[g];
    if (nct <= (unsigned)(c * PPB)) return;

    const int t = threadIdx.x, lane = t & 63, w = t >> 6;
    {
        const float* eg = emb + (size_t)g * 64 * 256;
        for (int i = t * 4; i < 16384; i += 1024) {
            const float4 v = *(const float4*)(eg + i);
            const int row = i >> 8, col = i & 255;
            *(float4*)(&es[row * 260 + col]) = v;
        }
    }
    __syncthreads();

    const unsigned* gl = list + g * 16384;
    for (unsigned base = c * PPB; base < nct; base += NCHUNK * PPB) {
        #pragma unroll 1
        for (int j = 0; j < 8; ++j) {
            const unsigned i = base + w * 8 + j;
            if (i >= nct || i >= base + PPB) continue;
            const unsigned n = gl[i];
            const float4 zv = *(const float4*)(zc + (size_t)n * 256 + lane * 4);
            *(float4*)(&zs[w][lane * 4]) = zv;
            const float zzv = zz[n];
            const float4* zr = (const float4*)(&zs[w][0]);
            const float4* er = (const float4*)(&es[lane * 260]);
            float4 a = {0.f, 0.f, 0.f, 0.f};
            #pragma unroll 8
            for (int c4 = 0; c4 < 64; ++c4) {
                const float4 e4 = er[c4];
                const float4 z4 = zr[c4];
                a.x = fmaf(z4.x, e4.x, a.x);
                a.y = fmaf(z4.y, e4.y, a.y);
                a.z = fmaf(z4.z, e4.z, a.z);
                a.w = fmaf(z4.w, e4.w, a.w);
            }
            const float dot = (a.x + a.y) + (a.z + a.w);
            const float d = fmaf(-2.f, dot, zzv);
            unsigned long long key =
                ((unsigned long long)__float_as_uint(d) << 32) | (unsigned)(g * 64 + lane);
            #pragma unroll
            for (int s = 1; s < 64; s <<= 1) {
                const unsigned long long o = __shfl_xor(key, s);
                if (o < key) key = o;
            }
            if (lane == 0) atomicMin(&best[n], key);
        }
    }
}

// ---------------------------------------------------------------------------
// rescore (fallback, verified)
// ---------------------------------------------------------------------------
__global__ __launch_bounds__(256) void k_rescore(const float* __restrict__ z,
                                                 const float* __restrict__ emb,
                                                 const float* __restrict__ zz,
                                                 const f16* __restrict__ gmaxT,
                                                 unsigned long long* __restrict__ best) {
    __shared__ float zsh[16][260];
    const int n0 = blockIdx.x * 16;
    const int b = n0 >> 10, hw0 = n0 & 1023;
    const int t = threadIdx.x, lane = t & 63, w = t >> 6;
    {
        const int p = t & 15, cq = t >> 4;
        const float* zp = z + (size_t)b * 262144 + hw0 + p;
        #pragma unroll
        for (int c = cq * 16; c < cq * 16 + 16; ++c)
            zsh[p][c] = zp[(size_t)c * 1024];
    }
    __syncthreads();
    for (int p = w; p < 16; p += 4) {
        const int n = n0 + p;
        const float g0 = (float)gmaxT[(size_t)lane * 16384 + n];
        const float g1 = (float)gmaxT[(size_t)(lane + 64) * 16384 + n];
        float m = fmaxf(g0, g1);
        #pragma unroll
        for (int s = 1; s < 64; s <<= 1) m = fmaxf(m, __shfl_xor(m, s));
        const float thr = m - MARGIN;
        unsigned long long f0 = __ballot(g0 >= thr);
        unsigned long long f1 = __ballot(g1 >= thr);
        const float zzv = zz[n];
        const float4* zr = (const float4*)(&zsh[p][0]);
        unsigned long long key = ~0ull;
        while (f0 | f1) {
            int g;
            if (f0) { g = __ffsll(f0) - 1; f0 &= f0 - 1; }
            else    { g = 64 + __ffsll(f1) - 1; f1 &= f1 - 1; }
            const float4* er = (const float4*)(emb + ((size_t)(g * 64 + lane) << 8));
            float4 a = {0.f, 0.f, 0.f, 0.f};
            #pragma unroll 8
            for (int c4 = 0; c4 < 64; ++c4) {
                const float4 e4 = er[c4];
                const float4 z4 = zr[c4];
                a.x = fmaf(z4.x, e4.x, a.x);
                a.y = fmaf(z4.y, e4.y, a.y);
                a.z = fmaf(z4.z, e4.z, a.z);
                a.w = fmaf(z4.w, e4.w, a.w);
            }
            const float dot = (a.x + a.y) + (a.z + a.w);
            const float d = fmaf(-2.f, dot, zzv);
            const unsigned long long kk =
                ((unsigned long long)__float_as_uint(d) << 32) | (unsigned)(g * 64 + lane);
            if (kk < key) key = kk;
        }
        #pragma unroll
        for (int s = 1; s < 64; s <<= 1) {
            const unsigned long long o = __shfl_xor(key, s);
            if (o < key) key = o;
        }
        if (lane == 0) best[n] = key;
    }
}

// ---------------------------------------------------------------------------
// out + loss (unchanged — verified exact)
// ---------------------------------------------------------------------------
__global__ __launch_bounds__(256) void k_out(const float* __restrict__ z,
                                             const float* __restrict__ emb,
                                             const unsigned long long* __restrict__ best,
                                             float* __restrict__ out0,
                                             float* __restrict__ out2,
                                             double* __restrict__ loss) {
    const int n0 = blockIdx.x * 64;
    const int b = n0 >> 10, hw0 = n0 & 1023;
    const int p = threadIdx.x & 63, cg = threadIdx.x >> 6;
    const int n = n0 + p;
    const int idx = (int)(unsigned)(best[n] & 0xffffffffull);
    if (threadIdx.x < 64)
        out2[n0 + threadIdx.x] =
            (float)(int)(unsigned)(best[n0 + threadIdx.x] & 0xffffffffull);

    const float* zb = z + b * 262144 + hw0 + p;
    float*       ob = out0 + b * 262144 + hw0 + p;
    const float* eb = emb + idx * 256;
    double ls = 0.0;
    #pragma unroll 4
    for (int c = cg * 64; c < cg * 64 + 64; ++c) {
        float zp = zb[c * 1024];
        float e  = eb[c];
        float diff = e - zp;
        ob[c * 1024] = zp + diff;
        float l = zp - e;
        ls += (double)l * (double)l;
    }
    __shared__ double red[256];
    red[threadIdx.x] = ls;
    __syncthreads();
    for (int s = 128; s > 0; s >>= 1) {
        if (threadIdx.x < s) red[threadIdx.x] += red[threadIdx.x + s];
        __syncthreads();
    }
    if (threadIdx.x == 0) atomicAdd(loss, red[0]);
}

__global__ void k_loss(const double* __restrict__ loss, float* __restrict__ out1) {
    float m = (float)(*loss / (double)NELEM);
    out1[0] = 0.25f * m + m;
}

// ---------------------------------------------------------------------------
extern "C" void kernel_launch(void* const* d_in, const int* in_sizes, int n_in,
                              void* d_out, int out_size, void* d_ws, size_t ws_size,
                              hipStream_t stream) {
    const float* z   = (const float*)d_in[0];
    const float* emb = (const float*)d_in[1];
    float* out  = (float*)d_out;
    float* out0 = out;
    float* out1 = out + NELEM;
    float* out2 = out + NELEM + 1;

    // out0 (16 MB) scratch: z16 (8 MB) | e16 (4 MB) | gmaxT (4 MB).
    // After gemm: z16 region -> candidate lists (8 MB); e16 region -> thr (64 KB).
    f16* z16    = (f16*)out0;
    f16* e16    = (f16*)((char*)out0 + 8388608);
    f16* gmaxT  = (f16*)((char*)out0 + 12582912);
    unsigned* list = (unsigned*)out0;
    float* thr  = (float*)((char*)out0 + 8388608);

    const size_t ZC_BYTES = 16777216;
    const bool fast = ws_size >= ZC_BYTES + 65536 + 131072 + 1024;

    if (fast) {
        float* zc = (float*)d_ws;                                        // 16 MB
        float* zzp = (float*)((char*)d_ws + ZC_BYTES);                   // 64 KB
        unsigned long long* best =
            (unsigned long long*)((char*)d_ws + ZC_BYTES + 65536);       // 128 KB
        unsigned* cnt = (unsigned*)((char*)d_ws + ZC_BYTES + 65536 + 131072);
        double* loss  = (double*)((char*)d_ws + ZC_BYTES + 65536 + 131072 + 512);

        hipMemsetAsync(best, 0xFF, NPTS * 8, stream);
        hipMemsetAsync(loss, 0, 8, stream);
        k_prep_z<<<256, 256, 0, stream>>>(z, z16, zzp, zc);
        k_prep_e<<<2048, 256, 0, stream>>>(emb, e16);
        k_gemm<<<8192, 256, 0, stream>>>(z16, e16, gmaxT);
        k_pmax<<<64, 256, 0, stream>>>(gmaxT, thr);
        k_build<<<128, 256, 0, stream>>>(gmaxT, thr, cnt, list);
        k_rescore2<<<128 * NCHUNK, 256, 0, stream>>>(emb, zc, zzp, cnt, list, best);
        k_out<<<256, 256, 0, stream>>>(z, emb, best, out0, out2, loss);
        k_loss<<<1, 1, 0, stream>>>(loss, out1);
    } else {
        float* zzp = (float*)d_ws;
        unsigned long long* best =
            (unsigned long long*)((char*)d_ws + 65536);
        double* loss = (double*)((char*)d_ws + 65536 + 131072);

        hipMemsetAsync(loss, 0, 8, stream);
        k_prep_z<<<256, 256, 0, stream>>>(z, z16, zzp, nullptr);
        k_prep_e<<<2048, 256, 0, stream>>>(emb, e16);
        k_gemm<<<8192, 256, 0, stream>>>(z16, e16, gmaxT);
        k_rescore<<<1024, 256, 0, stream>>>(z, emb, zzp, gmaxT, best);
        k_out<<<256, 256, 0, stream>>>(z, emb, best, out0, out2, loss);
        k_loss<<<1, 1, 0, stream>>>(loss, out1);
    }
}

// Round 8
// 232.690 us; speedup vs baseline: 1.0601x; 1.0429x over previous
//
#include <hip/hip_runtime.h>

#define BATCH   16
#define CDIM    256
#define NPTS    16384      // B*H*W
#define KCODES  8192
#define NELEM   4194304    // B*C*H*W
#define ESCALE  4096.0f
#define MARGIN  0.5f       // in S = 4096*dot units (worst-case error ~0.33)
#define PPB     64         // points per (group,chunk) batch
#define NCHUNK  4          // chunks per group

typedef _Float16 f16;
typedef _Float16 f16x8 __attribute__((ext_vector_type(8)));
typedef _Float16 f16x4 __attribute__((ext_vector_type(4)));
typedef float    f32x4 __attribute__((ext_vector_type(4)));

__device__ __forceinline__ void gload16(const void* g, void* l) {
    __builtin_amdgcn_global_load_lds(
        (const __attribute__((address_space(1))) unsigned int*)g,
        (__attribute__((address_space(3))) unsigned int*)l, 16, 0, 0);
}

__device__ __forceinline__ float rdlane(float v, int l) {
    return __uint_as_float(__builtin_amdgcn_readlane(__float_as_uint(v), l));
}

// ---------------------------------------------------------------------------
// prep_z: zz[n] + z16[n][c] (verified) + compact fp32 copy zc[n][c]
// ---------------------------------------------------------------------------
__global__ __launch_bounds__(256) void k_prep_z(const float* __restrict__ z,
                                                f16* __restrict__ z16,
                                                float* __restrict__ zz,
                                                float* __restrict__ zc) {
    __shared__ f16 tile[64][264];
    __shared__ float tile32[64][260];
    __shared__ float red[4][64];
    const int n0 = blockIdx.x * 64;
    const int b = n0 >> 10, hw0 = n0 & 1023;
    const int p = threadIdx.x & 63, g = threadIdx.x >> 6;
    const float* zb = z + b * 262144 + hw0 + p;
    float s = 0.f;
    for (int c = g * 64; c < g * 64 + 64; ++c) {
        float v = zb[c * 1024];
        s = fmaf(v, v, s);
        tile[p][c] = (f16)v;
        tile32[p][c] = v;
    }
    red[g][p] = s;
    __syncthreads();
    if (g == 0) zz[n0 + p] = (red[0][p] + red[1][p]) + (red[2][p] + red[3][p]);
    const int r = threadIdx.x >> 2, q = threadIdx.x & 3;
    f16* dst = z16 + (size_t)(n0 + r) * 256 + q * 64;
    #pragma unroll
    for (int j = 0; j < 8; ++j)
        *(f16x8*)(dst + j * 8) = *(const f16x8*)(&tile[r][q * 64 + j * 8]);
    if (zc) {
        const int w = threadIdx.x >> 6, l = threadIdx.x & 63;
        #pragma unroll
        for (int rr = 0; rr < 16; ++rr) {
            const int row = w * 16 + rr;
            *(float4*)(zc + (size_t)(n0 + row) * 256 + l * 4) =
                *(const float4*)(&tile32[row][l * 4]);
        }
    }
}

// ---------------------------------------------------------------------------
// prep_e: e16[k][c] = f16(emb * 4096)
// ---------------------------------------------------------------------------
__global__ __launch_bounds__(256) void k_prep_e(const float* __restrict__ emb,
                                                f16* __restrict__ e16) {
    const int i = (blockIdx.x * 256 + threadIdx.x) * 4;
    float4 v = *(const float4*)(emb + i);
    f16x4 o = {(f16)(v.x * ESCALE), (f16)(v.y * ESCALE),
               (f16)(v.z * ESCALE), (f16)(v.w * ESCALE)};
    *(f16x4*)(e16 + i) = o;
}

// ---------------------------------------------------------------------------
// gemm: S = z16 @ e16^T (R7-verified structure: 128x128 tile, 4 waves, BK=64
// single-buffered, XCD swizzle).  Epilogue now packs each wave's 4 q-values
// into one f16x4 8B store (kills the 9x partial-sector write amplification).
// ---------------------------------------------------------------------------
__global__ __launch_bounds__(256, 4) void k_gemm(const f16* __restrict__ z16,
                                                 const f16* __restrict__ e16,
                                                 f16* __restrict__ gmaxT) {
    __shared__ f16 As[8192];   // [128 rows][64 k] = 16 KB
    __shared__ f16 Bs[8192];   // 16 KB
    const int swz = (blockIdx.x & 7) * 1024 + (blockIdx.x >> 3);
    const int bm = swz >> 6, bn = swz & 63;
    const size_t m0 = (size_t)bm * 128, n0 = (size_t)bn * 128;
    const int t = threadIdx.x, lane = t & 63, w = t >> 6;
    const int wm = w >> 1, wn = w & 1;        // 2x2 waves, wave tile 64x64

    const f16* zg = z16 + m0 * 256;
    const f16* eg = e16 + n0 * 256;

    f32x4 acc[4][4] = {};

    for (int kt = 0; kt < 4; ++kt) {
        #pragma unroll
        for (int pp = 0; pp < 4; ++pp) {
            const int gi  = pp * 256 + t;
            const int row = gi >> 3;
            const int kc  = (gi & 7) ^ (row & 7);  // inverse swizzle on source
            const size_t goff = (size_t)row * 256 + (size_t)kt * 64 + kc * 8;
            gload16(zg + goff, (char*)As + gi * 16);
            gload16(eg + goff, (char*)Bs + gi * 16);
        }
        __syncthreads();
        #pragma unroll
        for (int kk = 0; kk < 2; ++kk) {
            f16x8 a[4], bf[4];
            const int kc = kk * 4 + (lane >> 4);
            #pragma unroll
            for (int mr = 0; mr < 4; ++mr) {
                const int row = wm * 64 + mr * 16 + (lane & 15);
                a[mr] = *(const f16x8*)((const char*)As + row * 128 + ((kc ^ (row & 7)) << 4));
            }
            #pragma unroll
            for (int nr = 0; nr < 4; ++nr) {
                const int row = wn * 64 + nr * 16 + (lane & 15);
                bf[nr] = *(const f16x8*)((const char*)Bs + row * 128 + ((kc ^ (row & 7)) << 4));
            }
            #pragma unroll
            for (int mr = 0; mr < 4; ++mr)
                #pragma unroll
                for (int nr = 0; nr < 4; ++nr)
                    acc[mr][nr] = __builtin_amdgcn_mfma_f32_16x16x32_f16(
                        a[mr], bf[nr], acc[mr][nr], 0, 0, 0);
        }
        __syncthreads();
    }

    // epilogue: per-point max over this wave's 64 codes, packed 8B stores
    const int g = bn * 2 + wn;
    #pragma unroll
    for (int mr = 0; mr < 4; ++mr) {
        f16x4 pk;
        #pragma unroll
        for (int q = 0; q < 4; ++q) {
            float v = acc[mr][0][q];
            v = fmaxf(v, acc[mr][1][q]);
            v = fmaxf(v, acc[mr][2][q]);
            v = fmaxf(v, acc[mr][3][q]);
            v = fmaxf(v, __shfl_xor(v, 1));
            v = fmaxf(v, __shfl_xor(v, 2));
            v = fmaxf(v, __shfl_xor(v, 4));
            v = fmaxf(v, __shfl_xor(v, 8));
            pk[q] = (f16)v;
        }
        if ((lane & 15) == 0) {
            const int p0 = wm * 64 + mr * 16 + ((lane >> 4) << 2);
            *(f16x4*)(gmaxT + (size_t)g * 16384 + m0 + p0) = pk;
        }
    }
}

// ---------------------------------------------------------------------------
// pmax: thr[n] = max_g gmaxT[g][n] - MARGIN; also init best[n] (no memset node)
// ---------------------------------------------------------------------------
__global__ __launch_bounds__(256) void k_pmax(const f16* __restrict__ gmaxT,
                                              float* __restrict__ thr,
                                              unsigned long long* __restrict__ best) {
    const int n = blockIdx.x * 256 + threadIdx.x;
    best[n] = ~0ull;
    float m = -1e30f;
    #pragma unroll 16
    for (int g = 0; g < 128; ++g)
        m = fmaxf(m, (float)gmaxT[(size_t)g * 16384 + n]);
    thr[n] = m - MARGIN;
}

// ---------------------------------------------------------------------------
// build: compact candidate lists; next-iteration row/thr register prefetch so
// loads overlap the barrier-bound compaction (was latency-serial).
// ---------------------------------------------------------------------------
__global__ __launch_bounds__(256) void k_build(const f16* __restrict__ gmaxT,
                                               const float* __restrict__ thr,
                                               unsigned* __restrict__ cnt,
                                               unsigned* __restrict__ list) {
    __shared__ unsigned wsum[4];
    const int g = blockIdx.x;
    const int t = threadIdx.x, lane = t & 63, w = t >> 6;
    const f16* row = gmaxT + (size_t)g * 16384;
    unsigned* gl = list + (size_t)g * 16384;
    unsigned run = 0;
    float rv = (float)row[t], tv = thr[t];
    for (int c = 0; c < 64; ++c) {
        const int n = c * 256 + t;
        float rn = 0.f, tn = 1.f;
        if (c < 63) { rn = (float)row[n + 256]; tn = thr[n + 256]; }
        const bool f = rv >= tv;
        const unsigned long long mk = __ballot(f);
        if (lane == 0) wsum[w] = (unsigned)__popcll(mk);
        __syncthreads();
        const unsigned w0 = wsum[0], w1 = wsum[1], w2 = wsum[2], w3 = wsum[3];
        if (f) {
            const unsigned wexcl = (w > 0 ? w0 : 0u) + (w > 1 ? w1 : 0u) + (w > 2 ? w2 : 0u);
            const unsigned rank = (unsigned)__popcll(mk & ((1ull << lane) - 1ull));
            gl[run + wexcl + rank] = (unsigned)n;
        }
        run += w0 + w1 + w2 + w3;
        __syncthreads();
        rv = rn; tv = tn;
    }
    if (t == 0) cnt[g] = run;
}

// ---------------------------------------------------------------------------
// rescore2 (group-major): LDS-resident emb group; z row broadcast via
// readlane (lane c4 holds z[4c4..4c4+3]) — no LDS z buffer, no write hazard,
// identical fp32 accumulation order to the verified version.
// ---------------------------------------------------------------------------
__global__ __launch_bounds__(256) void k_rescore2(const float* __restrict__ emb,
                                                  const float* __restrict__ zc,
                                                  const float* __restrict__ zz,
                                                  const unsigned* __restrict__ cnt,
                                                  const unsigned* __restrict__ list,
                                                  unsigned long long* __restrict__ best) {
    __shared__ float es[64 * 260];
    const int g = blockIdx.x >> 2, c = blockIdx.x & 3;
    const unsigned nct = cnt[g];
    if (nct <= (unsigned)(c * PPB)) return;

    const int t = threadIdx.x, lane = t & 63, w = t >> 6;
    {
        const float* eg = emb + (size_t)g * 64 * 256;
        for (int i = t * 4; i < 16384; i += 1024) {
            const float4 v = *(const float4*)(eg + i);
            const int row = i >> 8, col = i & 255;
            *(float4*)(&es[row * 260 + col]) = v;
        }
    }
    __syncthreads();

    const unsigned* gl = list + g * 16384;
    const float4* er = (const float4*)(&es[lane * 260]);
    for (unsigned base = c * PPB; base < nct; base += NCHUNK * PPB) {
        for (int j = 0; j < PPB / 4; ++j) {
            const unsigned i = base + w * (PPB / 4) + j;
            if (i >= nct || i >= base + PPB) continue;
            const unsigned n = gl[i];
            const float4 zv = *(const float4*)(zc + (size_t)n * 256 + lane * 4);
            const float zzv = zz[n];
            float4 a = {0.f, 0.f, 0.f, 0.f};
            #pragma unroll 16
            for (int c4 = 0; c4 < 64; ++c4) {
                const float4 e4 = er[c4];
                a.x = fmaf(rdlane(zv.x, c4), e4.x, a.x);
                a.y = fmaf(rdlane(zv.y, c4), e4.y, a.y);
                a.z = fmaf(rdlane(zv.z, c4), e4.z, a.z);
                a.w = fmaf(rdlane(zv.w, c4), e4.w, a.w);
            }
            const float dot = (a.x + a.y) + (a.z + a.w);
            const float d = fmaf(-2.f, dot, zzv);
            unsigned long long key =
                ((unsigned long long)__float_as_uint(d) << 32) | (unsigned)(g * 64 + lane);
            #pragma unroll
            for (int s = 1; s < 64; s <<= 1) {
                const unsigned long long o = __shfl_xor(key, s);
                if (o < key) key = o;
            }
            if (lane == 0) atomicMin(&best[n], key);
        }
    }
}

// ---------------------------------------------------------------------------
// rescore (fallback, verified)
// ---------------------------------------------------------------------------
__global__ __launch_bounds__(256) void k_rescore(const float* __restrict__ z,
                                                 const float* __restrict__ emb,
                                                 const float* __restrict__ zz,
                                                 const f16* __restrict__ gmaxT,
                                                 unsigned long long* __restrict__ best) {
    __shared__ float zsh[16][260];
    const int n0 = blockIdx.x * 16;
    const int b = n0 >> 10, hw0 = n0 & 1023;
    const int t = threadIdx.x, lane = t & 63, w = t >> 6;
    {
        const int p = t & 15, cq = t >> 4;
        const float* zp = z + (size_t)b * 262144 + hw0 + p;
        #pragma unroll
        for (int c = cq * 16; c < cq * 16 + 16; ++c)
            zsh[p][c] = zp[(size_t)c * 1024];
    }
    __syncthreads();
    for (int p = w; p < 16; p += 4) {
        const int n = n0 + p;
        const float g0 = (float)gmaxT[(size_t)lane * 16384 + n];
        const float g1 = (float)gmaxT[(size_t)(lane + 64) * 16384 + n];
        float m = fmaxf(g0, g1);
        #pragma unroll
        for (int s = 1; s < 64; s <<= 1) m = fmaxf(m, __shfl_xor(m, s));
        const float thr = m - MARGIN;
        unsigned long long f0 = __ballot(g0 >= thr);
        unsigned long long f1 = __ballot(g1 >= thr);
        const float zzv = zz[n];
        const float4* zr = (const float4*)(&zsh[p][0]);
        unsigned long long key = ~0ull;
        while (f0 | f1) {
            int g;
            if (f0) { g = __ffsll(f0) - 1; f0 &= f0 - 1; }
            else    { g = 64 + __ffsll(f1) - 1; f1 &= f1 - 1; }
            const float4* er = (const float4*)(emb + ((size_t)(g * 64 + lane) << 8));
            float4 a = {0.f, 0.f, 0.f, 0.f};
            #pragma unroll 8
            for (int c4 = 0; c4 < 64; ++c4) {
                const float4 e4 = er[c4];
                const float4 z4 = zr[c4];
                a.x = fmaf(z4.x, e4.x, a.x);
                a.y = fmaf(z4.y, e4.y, a.y);
                a.z = fmaf(z4.z, e4.z, a.z);
                a.w = fmaf(z4.w, e4.w, a.w);
            }
            const float dot = (a.x + a.y) + (a.z + a.w);
            const float d = fmaf(-2.f, dot, zzv);
            const unsigned long long kk =
                ((unsigned long long)__float_as_uint(d) << 32) | (unsigned)(g * 64 + lane);
            if (kk < key) key = kk;
        }
        #pragma unroll
        for (int s = 1; s < 64; s <<= 1) {
            const unsigned long long o = __shfl_xor(key, s);
            if (o < key) key = o;
        }
        if (lane == 0) best[n] = key;
    }
}

// ---------------------------------------------------------------------------
// out + per-block loss partial (no same-address atomic)
// ---------------------------------------------------------------------------
__global__ __launch_bounds__(256) void k_out(const float* __restrict__ z,
                                             const float* __restrict__ emb,
                                             const unsigned long long* __restrict__ best,
                                             float* __restrict__ out0,
                                             float* __restrict__ out2,
                                             double* __restrict__ lossp) {
    const int n0 = blockIdx.x * 64;
    const int b = n0 >> 10, hw0 = n0 & 1023;
    const int p = threadIdx.x & 63, cg = threadIdx.x >> 6;
    const int n = n0 + p;
    const int idx = (int)(unsigned)(best[n] & 0xffffffffull);
    if (threadIdx.x < 64)
        out2[n0 + threadIdx.x] =
            (float)(int)(unsigned)(best[n0 + threadIdx.x] & 0xffffffffull);

    const float* zb = z + b * 262144 + hw0 + p;
    float*       ob = out0 + b * 262144 + hw0 + p;
    const float* eb = emb + idx * 256;
    double ls = 0.0;
    #pragma unroll 4
    for (int c = cg * 64; c < cg * 64 + 64; ++c) {
        float zp = zb[c * 1024];
        float e  = eb[c];
        float diff = e - zp;
        ob[c * 1024] = zp + diff;
        float l = zp - e;
        ls += (double)l * (double)l;
    }
    __shared__ double red[256];
    red[threadIdx.x] = ls;
    __syncthreads();
    for (int s = 128; s > 0; s >>= 1) {
        if (threadIdx.x < s) red[threadIdx.x] += red[threadIdx.x + s];
        __syncthreads();
    }
    if (threadIdx.x == 0) lossp[blockIdx.x] = red[0];
}

__global__ __launch_bounds__(256) void k_loss(const double* __restrict__ lossp,
                                              float* __restrict__ out1) {
    __shared__ double red[256];
    red[threadIdx.x] = lossp[threadIdx.x];
    __syncthreads();
    for (int s = 128; s > 0; s >>= 1) {
        if (threadIdx.x < s) red[threadIdx.x] += red[threadIdx.x + s];
        __syncthreads();
    }
    if (threadIdx.x == 0) {
        float m = (float)(red[0] / (double)NELEM);
        out1[0] = 0.25f * m + m;
    }
}

// ---------------------------------------------------------------------------
extern "C" void kernel_launch(void* const* d_in, const int* in_sizes, int n_in,
                              void* d_out, int out_size, void* d_ws, size_t ws_size,
                              hipStream_t stream) {
    const float* z   = (const float*)d_in[0];
    const float* emb = (const float*)d_in[1];
    float* out  = (float*)d_out;
    float* out0 = out;
    float* out1 = out + NELEM;
    float* out2 = out + NELEM + 1;

    // out0 (16 MB) scratch: z16 (8 MB) | e16 (4 MB) | gmaxT (4 MB).
    // After gemm: z16 region -> candidate lists (8 MB); e16 region -> thr (64 KB).
    f16* z16    = (f16*)out0;
    f16* e16    = (f16*)((char*)out0 + 8388608);
    f16* gmaxT  = (f16*)((char*)out0 + 12582912);
    unsigned* list = (unsigned*)out0;
    float* thr  = (float*)((char*)out0 + 8388608);

    const size_t ZC_BYTES = 16777216;
    const bool fast = ws_size >= ZC_BYTES + 65536 + 131072 + 4096;

    if (fast) {
        float* zc = (float*)d_ws;                                        // 16 MB
        float* zzp = (float*)((char*)d_ws + ZC_BYTES);                   // 64 KB
        unsigned long long* best =
            (unsigned long long*)((char*)d_ws + ZC_BYTES + 65536);       // 128 KB
        unsigned* cnt = (unsigned*)((char*)d_ws + ZC_BYTES + 65536 + 131072);
        double* lossp = (double*)((char*)d_ws + ZC_BYTES + 65536 + 131072 + 512);

        k_prep_z<<<256, 256, 0, stream>>>(z, z16, zzp, zc);
        k_prep_e<<<2048, 256, 0, stream>>>(emb, e16);
        k_gemm<<<8192, 256, 0, stream>>>(z16, e16, gmaxT);
        k_pmax<<<64, 256, 0, stream>>>(gmaxT, thr, best);
        k_build<<<128, 256, 0, stream>>>(gmaxT, thr, cnt, list);
        k_rescore2<<<128 * NCHUNK, 256, 0, stream>>>(emb, zc, zzp, cnt, list, best);
        k_out<<<256, 256, 0, stream>>>(z, emb, best, out0, out2, lossp);
        k_loss<<<1, 256, 0, stream>>>(lossp, out1);
    } else {
        float* zzp = (float*)d_ws;
        unsigned long long* best =
            (unsigned long long*)((char*)d_ws + 65536);
        double* lossp = (double*)((char*)d_ws + 65536 + 131072);

        k_prep_z<<<256, 256, 0, stream>>>(z, z16, zzp, nullptr);
        k_prep_e<<<2048, 256, 0, stream>>>(emb, e16);
        k_gemm<<<8192, 256, 0, stream>>>(z16, e16, gmaxT);
        k_rescore<<<1024, 256, 0, stream>>>(z, emb, zzp, gmaxT, best);
        k_out<<<256, 256, 0, stream>>>(z, emb, best, out0, out2, lossp);
        k_loss<<<1, 256, 0, stream>>>(lossp, out1);
    }
}